// Round 1
// baseline (939.476 us; speedup 1.0000x reference)
//
#include <hip/hip_runtime.h>
#include <math.h>

#define NN 50000
#define NE 640000
#define NR 8

// ---- repack W[r][d][o] -> Wb[d][r*O+o] so einsum('nd,rdo->nro') is one GEMM
__global__ __launch_bounds__(256) void repack_kernel(const float* __restrict__ W,
                                                     float* __restrict__ Wb,
                                                     int R, int D, int O) {
    int i = blockIdx.x * 256 + threadIdx.x;
    int total = R * D * O;
    if (i >= total) return;
    int o = i % O;
    int d = (i / O) % D;
    int r = i / (O * D);
    Wb[d * (R * O) + r * O + o] = W[i];
}

__global__ __launch_bounds__(256) void count_kernel(const int* __restrict__ dst,
                                                    const int* __restrict__ typ,
                                                    int* __restrict__ cnt, int E, int R) {
    int e = blockIdx.x * 256 + threadIdx.x;
    if (e < E) atomicAdd(&cnt[dst[e] * R + typ[e]], 1);
}

__global__ __launch_bounds__(256) void inv_kernel(const int* __restrict__ cnt,
                                                  float* __restrict__ inv, int n) {
    int i = blockIdx.x * 256 + threadIdx.x;
    if (i < n) {
        int c = cnt[i];
        inv[i] = 1.0f / (float)(c > 1 ? c : 1);
    }
}

// ---- C[M,N] = A[M,128] @ B[128,N] (+ bias), fp32. BM=BN=64, 256 thr, 4x4 micro-tile.
__global__ __launch_bounds__(256) void gemm_k128(const float* __restrict__ A,
                                                 const float* __restrict__ B,
                                                 const float* __restrict__ bias,
                                                 float* __restrict__ C, int M, int N) {
    // As padded to 132 floats/row: row stride mod 32 banks = 4 -> the 4 distinct
    // rows a wave touches per k land on 2 banks x 2 addrs (2-way = free, m136).
    __shared__ float As[64][132];
    __shared__ float Bs[128][64];
    const int bm = blockIdx.y * 64;
    const int bn = blockIdx.x * 64;
    const int t = threadIdx.x;

    // load A tile 64x128 (2048 float4)
    for (int i = t; i < 2048; i += 256) {
        int r = i >> 5, c4 = i & 31;
        int gr = bm + r;
        float4 v = make_float4(0.f, 0.f, 0.f, 0.f);
        if (gr < M) v = ((const float4*)(A + (size_t)gr * 128))[c4];
        ((float4*)&As[r][0])[c4] = v;
    }
    // load B tile 128x64 (2048 float4)
    for (int i = t; i < 2048; i += 256) {
        int r = i >> 4, c4 = i & 15;
        float4 v = ((const float4*)(B + (size_t)r * N + bn))[c4];
        ((float4*)&Bs[r][0])[c4] = v;
    }
    __syncthreads();

    const int ti = t >> 4, tj = t & 15;
    float acc[4][4] = {};
#pragma unroll 8
    for (int k = 0; k < 128; ++k) {
        float a0 = As[4 * ti + 0][k];
        float a1 = As[4 * ti + 1][k];
        float a2 = As[4 * ti + 2][k];
        float a3 = As[4 * ti + 3][k];
        float4 b = ((const float4*)&Bs[k][0])[tj];
        acc[0][0] += a0 * b.x; acc[0][1] += a0 * b.y; acc[0][2] += a0 * b.z; acc[0][3] += a0 * b.w;
        acc[1][0] += a1 * b.x; acc[1][1] += a1 * b.y; acc[1][2] += a1 * b.z; acc[1][3] += a1 * b.w;
        acc[2][0] += a2 * b.x; acc[2][1] += a2 * b.y; acc[2][2] += a2 * b.z; acc[2][3] += a2 * b.w;
        acc[3][0] += a3 * b.x; acc[3][1] += a3 * b.y; acc[3][2] += a3 * b.z; acc[3][3] += a3 * b.w;
    }

    float4 bv = make_float4(0.f, 0.f, 0.f, 0.f);
    if (bias) bv = ((const float4*)(bias + bn))[tj];
#pragma unroll
    for (int m = 0; m < 4; ++m) {
        int gr = bm + 4 * ti + m;
        if (gr < M) {
            float4 o;
            o.x = acc[m][0] + bv.x;
            o.y = acc[m][1] + bv.y;
            o.z = acc[m][2] + bv.z;
            o.w = acc[m][3] + bv.w;
            ((float4*)(C + (size_t)gr * N + bn))[tj] = o;
        }
    }
}

// ---- one wave per edge: H[dst,:] += X[src, rel*O : rel*O+O] * inv[dst*R+rel]
__global__ __launch_bounds__(256) void scatter_kernel(const int* __restrict__ src,
                                                      const int* __restrict__ dst,
                                                      const int* __restrict__ typ,
                                                      const float* __restrict__ inv,
                                                      const float* __restrict__ X,
                                                      float* __restrict__ H,
                                                      int E, int R, int O) {
    int w = (blockIdx.x * 256 + threadIdx.x) >> 6;
    int lane = threadIdx.x & 63;
    if (w >= E) return;
    int s = src[w], d = dst[w], r = typ[w];
    float sc = inv[d * R + r];
    const float* xp = X + (size_t)s * (R * O) + (size_t)r * O;
    float* hp = H + (size_t)d * O;
    for (int o = lane; o < O; o += 64)
        atomicAdd(&hp[o], xp[o] * sc);
}

__global__ __launch_bounds__(256) void sigmoid_kernel(float* __restrict__ y, int n) {
    int i = blockIdx.x * 256 + threadIdx.x;
    if (i < n) y[i] = 1.0f / (1.0f + expf(-y[i]));
}

extern "C" void kernel_launch(void* const* d_in, const int* in_sizes, int n_in,
                              void* d_out, int out_size, void* d_ws, size_t ws_size,
                              hipStream_t stream) {
    const float* x     = (const float*)d_in[0];
    const int*   esrc  = (const int*)d_in[1];
    const int*   edst  = (const int*)d_in[2];
    const int*   etyp  = (const int*)d_in[3];
    const float* W1    = (const float*)d_in[4];
    const float* root1 = (const float*)d_in[5];
    const float* b1    = (const float*)d_in[6];
    const float* W2    = (const float*)d_in[7];
    const float* root2 = (const float*)d_in[8];
    const float* b2    = (const float*)d_in[9];
    float* out = (float*)d_out;

    // workspace carve-up (all chunks 256B-aligned sizes); xW2 aliases xW1.
    char* ws = (char*)d_ws;
    float* Wb1 = (float*)ws; ws += (size_t)128 * 1024 * 4;   // 512 KB
    float* Wb2 = (float*)ws; ws += (size_t)128 * 512 * 4;    // 256 KB
    int*   cnt = (int*)ws;   ws += (size_t)NN * NR * 4;      // 1.6 MB
    float* inv = (float*)ws; ws += (size_t)NN * NR * 4;      // 1.6 MB
    float* h1  = (float*)ws; ws += (size_t)NN * 128 * 4;     // 25.6 MB
    float* xW1 = (float*)ws;                                 // 204.8 MB
    float* xW2 = xW1;                                        // reuse after scatter1

    // degree counts (shared by both layers) -> inv
    hipMemsetAsync(cnt, 0, (size_t)NN * NR * 4, stream);
    count_kernel<<<(NE + 255) / 256, 256, 0, stream>>>(edst, etyp, cnt, NE, NR);
    inv_kernel<<<(NN * NR + 255) / 256, 256, 0, stream>>>(cnt, inv, NN * NR);

    // weight repacks
    repack_kernel<<<(NR * 128 * 128 + 255) / 256, 256, 0, stream>>>(W1, Wb1, NR, 128, 128);
    repack_kernel<<<(NR * 128 * 64 + 255) / 256, 256, 0, stream>>>(W2, Wb2, NR, 128, 64);

    dim3 blk(256);
    int gy = (NN + 63) / 64;

    // layer 1: h1 = x@root1 + b1 (init), xW1 = x@Wb1, scatter mean-messages into h1
    gemm_k128<<<dim3(128 / 64, gy), blk, 0, stream>>>(x, root1, b1, h1, NN, 128);
    gemm_k128<<<dim3(1024 / 64, gy), blk, 0, stream>>>(x, Wb1, nullptr, xW1, NN, 1024);
    scatter_kernel<<<(NE * 64 + 255) / 256, blk, 0, stream>>>(esrc, edst, etyp, inv, xW1, h1,
                                                              NE, NR, 128);

    // layer 2: out = h1@root2 + b2 (init), xW2 = h1@Wb2, scatter into out, sigmoid
    gemm_k128<<<dim3(512 / 64, gy), blk, 0, stream>>>(h1, Wb2, nullptr, xW2, NN, 512);
    gemm_k128<<<dim3(64 / 64, gy), blk, 0, stream>>>(h1, root2, b2, out, NN, 64);
    scatter_kernel<<<(NE * 64 + 255) / 256, blk, 0, stream>>>(esrc, edst, etyp, inv, xW2, out,
                                                              NE, NR, 64);
    sigmoid_kernel<<<(NN * 64 + 255) / 256, blk, 0, stream>>>(out, NN * 64);
}

// Round 2
// 805.484 us; speedup vs baseline: 1.1664x; 1.1664x over previous
//
#include <hip/hip_runtime.h>
#include <math.h>

#define NN 50000
#define NE 640000
#define NR 8

// ---- repack W[r][d][o] -> Wb[d][r*O+o] so einsum('nd,rdo->nro') is one GEMM
__global__ __launch_bounds__(256) void repack_kernel(const float* __restrict__ W,
                                                     float* __restrict__ Wb,
                                                     int R, int D, int O) {
    int i = blockIdx.x * 256 + threadIdx.x;
    int total = R * D * O;
    if (i >= total) return;
    int o = i % O;
    int d = (i / O) % D;
    int r = i / (O * D);
    Wb[d * (R * O) + r * O + o] = W[i];
}

__global__ __launch_bounds__(256) void count_kernel(const int* __restrict__ dst,
                                                    const int* __restrict__ typ,
                                                    int* __restrict__ cnt, int E, int R) {
    int e = blockIdx.x * 256 + threadIdx.x;
    if (e < E) atomicAdd(&cnt[dst[e] * R + typ[e]], 1);
}

__global__ __launch_bounds__(256) void inv_kernel(const int* __restrict__ cnt,
                                                  float* __restrict__ inv, int n) {
    int i = blockIdx.x * 256 + threadIdx.x;
    if (i < n) {
        int c = cnt[i];
        inv[i] = 1.0f / (float)(c > 1 ? c : 1);
    }
}

// deg[n] = sum_r cnt[n*8+r]
__global__ __launch_bounds__(256) void deg_kernel(const int* __restrict__ cnt,
                                                  int* __restrict__ deg, int n) {
    int i = blockIdx.x * 256 + threadIdx.x;
    if (i < n) {
        int s = 0;
#pragma unroll
        for (int r = 0; r < NR; ++r) s += cnt[i * NR + r];
        deg[i] = s;
    }
}

// single-block exclusive scan over deg[0..n) -> rowptr[0..n], rowptr[n]=total
__global__ __launch_bounds__(1024) void scan_kernel(const int* __restrict__ deg,
                                                    int* __restrict__ rowptr, int n) {
    __shared__ int partial[1024];
    int t = threadIdx.x;
    int chunk = (n + 1023) / 1024;
    int lo = t * chunk;
    int hi = lo + chunk; if (hi > n) hi = n;
    int s = 0;
    for (int i = lo; i < hi; ++i) s += deg[i];
    partial[t] = s;
    __syncthreads();
    for (int off = 1; off < 1024; off <<= 1) {
        int v = (t >= off) ? partial[t - off] : 0;
        __syncthreads();
        partial[t] += v;
        __syncthreads();
    }
    int run = (t == 0) ? 0 : partial[t - 1];
    for (int i = lo; i < hi; ++i) { rowptr[i] = run; run += deg[i]; }
    if (t == 0) rowptr[n] = partial[1023];
}

__global__ __launch_bounds__(256) void copy_kernel(const int* __restrict__ a,
                                                   int* __restrict__ b, int n) {
    int i = blockIdx.x * 256 + threadIdx.x;
    if (i < n) b[i] = a[i];
}

// counting-sort fill: srcrel[pos] = src | rel<<20, pos = start[dst]++
__global__ __launch_bounds__(256) void fill_kernel(const int* __restrict__ src,
                                                   const int* __restrict__ dst,
                                                   const int* __restrict__ typ,
                                                   int* __restrict__ start,
                                                   int* __restrict__ srcrel, int E) {
    int e = blockIdx.x * 256 + threadIdx.x;
    if (e >= E) return;
    int d = dst[e];
    int pos = atomicAdd(&start[d], 1);
    srcrel[pos] = src[e] | (typ[e] << 20);
}

// ---- C[M,N] = A[M,128] @ B[128,N] (+ bias), fp32. BM=BN=64, 256 thr, 4x4 micro-tile.
__global__ __launch_bounds__(256) void gemm_k128(const float* __restrict__ A,
                                                 const float* __restrict__ B,
                                                 const float* __restrict__ bias,
                                                 float* __restrict__ C, int M, int N) {
    __shared__ float As[64][132];
    __shared__ float Bs[128][64];
    const int bm = blockIdx.y * 64;
    const int bn = blockIdx.x * 64;
    const int t = threadIdx.x;

    for (int i = t; i < 2048; i += 256) {
        int r = i >> 5, c4 = i & 31;
        int gr = bm + r;
        float4 v = make_float4(0.f, 0.f, 0.f, 0.f);
        if (gr < M) v = ((const float4*)(A + (size_t)gr * 128))[c4];
        ((float4*)&As[r][0])[c4] = v;
    }
    for (int i = t; i < 2048; i += 256) {
        int r = i >> 4, c4 = i & 15;
        float4 v = ((const float4*)(B + (size_t)r * N + bn))[c4];
        ((float4*)&Bs[r][0])[c4] = v;
    }
    __syncthreads();

    const int ti = t >> 4, tj = t & 15;
    float acc[4][4] = {};
#pragma unroll 8
    for (int k = 0; k < 128; ++k) {
        float a0 = As[4 * ti + 0][k];
        float a1 = As[4 * ti + 1][k];
        float a2 = As[4 * ti + 2][k];
        float a3 = As[4 * ti + 3][k];
        float4 b = ((const float4*)&Bs[k][0])[tj];
        acc[0][0] += a0 * b.x; acc[0][1] += a0 * b.y; acc[0][2] += a0 * b.z; acc[0][3] += a0 * b.w;
        acc[1][0] += a1 * b.x; acc[1][1] += a1 * b.y; acc[1][2] += a1 * b.z; acc[1][3] += a1 * b.w;
        acc[2][0] += a2 * b.x; acc[2][1] += a2 * b.y; acc[2][2] += a2 * b.z; acc[2][3] += a2 * b.w;
        acc[3][0] += a3 * b.x; acc[3][1] += a3 * b.y; acc[3][2] += a3 * b.z; acc[3][3] += a3 * b.w;
    }

    float4 bv = make_float4(0.f, 0.f, 0.f, 0.f);
    if (bias) bv = ((const float4*)(bias + bn))[tj];
#pragma unroll
    for (int m = 0; m < 4; ++m) {
        int gr = bm + 4 * ti + m;
        if (gr < M) {
            float4 o;
            o.x = acc[m][0] + bv.x;
            o.y = acc[m][1] + bv.y;
            o.z = acc[m][2] + bv.z;
            o.w = acc[m][3] + bv.w;
            ((float4*)(C + (size_t)gr * N + bn))[tj] = o;
        }
    }
}

// ---- gather-side segment reduce: one wave per dst node, no atomics.
// H[dst,:] (pre-filled with x@root+b) += sum_e X[src_e, rel_e, :] * inv[dst*8+rel_e]
template <int O>
__global__ __launch_bounds__(256) void reduce_kernel(const int* __restrict__ rowptr,
                                                     const int* __restrict__ srcrel,
                                                     const float* __restrict__ inv,
                                                     const float* __restrict__ X,
                                                     float* __restrict__ H) {
    int w = (blockIdx.x * 256 + threadIdx.x) >> 6;
    int lane = threadIdx.x & 63;
    if (w >= NN) return;
    int beg = rowptr[w], end = rowptr[w + 1];
    float* hp = H + (size_t)w * O;

    if (O == 128) {
        float2 acc = ((float2*)hp)[lane];
        for (int i = beg; i < end; ++i) {
            int pr = srcrel[i];
            int s = pr & 0xFFFFF, r = pr >> 20;
            float sc = inv[w * NR + r];
            float2 xp = ((const float2*)(X + (size_t)s * (NR * O) + (size_t)r * O))[lane];
            acc.x += xp.x * sc;
            acc.y += xp.y * sc;
        }
        ((float2*)hp)[lane] = acc;
    } else {
        float acc = hp[lane];
        for (int i = beg; i < end; ++i) {
            int pr = srcrel[i];
            int s = pr & 0xFFFFF, r = pr >> 20;
            float sc = inv[w * NR + r];
            acc += X[(size_t)s * (NR * O) + (size_t)r * O + lane] * sc;
        }
        hp[lane] = acc;
    }
}

__global__ __launch_bounds__(256) void sigmoid_kernel(float* __restrict__ y, int n) {
    int i = blockIdx.x * 256 + threadIdx.x;
    if (i < n) y[i] = 1.0f / (1.0f + expf(-y[i]));
}

extern "C" void kernel_launch(void* const* d_in, const int* in_sizes, int n_in,
                              void* d_out, int out_size, void* d_ws, size_t ws_size,
                              hipStream_t stream) {
    const float* x     = (const float*)d_in[0];
    const int*   esrc  = (const int*)d_in[1];
    const int*   edst  = (const int*)d_in[2];
    const int*   etyp  = (const int*)d_in[3];
    const float* W1    = (const float*)d_in[4];
    const float* root1 = (const float*)d_in[5];
    const float* b1    = (const float*)d_in[6];
    const float* W2    = (const float*)d_in[7];
    const float* root2 = (const float*)d_in[8];
    const float* b2    = (const float*)d_in[9];
    float* out = (float*)d_out;

    // workspace carve-up; xW2 aliases xW1.
    char* ws = (char*)d_ws;
    float* Wb1    = (float*)ws; ws += (size_t)128 * 1024 * 4;   // 512 KB
    float* Wb2    = (float*)ws; ws += (size_t)128 * 512 * 4;    // 256 KB
    int*   cnt    = (int*)ws;   ws += (size_t)NN * NR * 4;      // 1.6 MB
    float* inv    = (float*)ws; ws += (size_t)NN * NR * 4;      // 1.6 MB
    int*   deg    = (int*)ws;   ws += (size_t)NN * 4;           // 0.2 MB
    int*   rowptr = (int*)ws;   ws += (size_t)(NN + 4) * 4;     // 0.2 MB
    int*   start  = (int*)ws;   ws += (size_t)NN * 4;           // 0.2 MB
    int*   srcrel = (int*)ws;   ws += (size_t)NE * 4;           // 2.56 MB
    float* h1     = (float*)ws; ws += (size_t)NN * 128 * 4;     // 25.6 MB
    float* xW1    = (float*)ws;                                 // 204.8 MB
    float* xW2    = xW1;

    // degree counts per (dst,rel) -> inv; per-dst deg -> CSR rowptr; fill sorted src|rel
    hipMemsetAsync(cnt, 0, (size_t)NN * NR * 4, stream);
    count_kernel<<<(NE + 255) / 256, 256, 0, stream>>>(edst, etyp, cnt, NE, NR);
    inv_kernel<<<(NN * NR + 255) / 256, 256, 0, stream>>>(cnt, inv, NN * NR);
    deg_kernel<<<(NN + 255) / 256, 256, 0, stream>>>(cnt, deg, NN);
    scan_kernel<<<1, 1024, 0, stream>>>(deg, rowptr, NN);
    copy_kernel<<<(NN + 255) / 256, 256, 0, stream>>>(rowptr, start, NN);
    fill_kernel<<<(NE + 255) / 256, 256, 0, stream>>>(esrc, edst, etyp, start, srcrel, NE);

    // weight repacks
    repack_kernel<<<(NR * 128 * 128 + 255) / 256, 256, 0, stream>>>(W1, Wb1, NR, 128, 128);
    repack_kernel<<<(NR * 128 * 64 + 255) / 256, 256, 0, stream>>>(W2, Wb2, NR, 128, 64);

    dim3 blk(256);
    int gy = (NN + 63) / 64;
    int rgrid = (NN * 64 + 255) / 256;

    // layer 1: h1 = x@root1 + b1, xW1 = x@Wb1, gather-reduce into h1
    gemm_k128<<<dim3(128 / 64, gy), blk, 0, stream>>>(x, root1, b1, h1, NN, 128);
    gemm_k128<<<dim3(1024 / 64, gy), blk, 0, stream>>>(x, Wb1, nullptr, xW1, NN, 1024);
    reduce_kernel<128><<<rgrid, blk, 0, stream>>>(rowptr, srcrel, inv, xW1, h1);

    // layer 2: out = h1@root2 + b2, xW2 = h1@Wb2, gather-reduce into out, sigmoid
    gemm_k128<<<dim3(512 / 64, gy), blk, 0, stream>>>(h1, Wb2, nullptr, xW2, NN, 512);
    gemm_k128<<<dim3(64 / 64, gy), blk, 0, stream>>>(h1, root2, b2, out, NN, 64);
    reduce_kernel<64><<<rgrid, blk, 0, stream>>>(rowptr, srcrel, inv, xW2, out);
    sigmoid_kernel<<<(NN * 64 + 255) / 256, blk, 0, stream>>>(out, NN * 64);
}